// Round 22
// baseline (1093.010 us; speedup 1.0000x reference)
//
#include <hip/hip_runtime.h>
#include <hip/hip_bf16.h>
#include <cstdint>

#define NNODES 100000
#define NEDGES 1000000
#define HDIM 64
#define ODIM 16
#define NB 8
#define NREL 90
#define KDIM (HDIM * NB)   // 512 = GEMM inner dim, k = i*8 + b
#define CPAD 16            // cursor padding: one counter per 64B line
#define NRANGE 8           // dst ranges (== XCD count heuristic)
#define RANGE ((NNODES + NRANGE - 1) / NRANGE)   // 12500 nodes/range

typedef short short8 __attribute__((ext_vector_type(8)));
typedef float f32x4  __attribute__((ext_vector_type(4)));
union FragU { uint4 u; short8 s; };

__device__ __forceinline__ float asf(uint32_t u) { float f; __builtin_memcpy(&f, &u, 4); return f; }
__device__ __forceinline__ uint32_t asu(float f) { uint32_t u; __builtin_memcpy(&u, &f, 4); return u; }
__device__ __forceinline__ uint16_t f2bf(float f) {
    uint32_t x = asu(f);
    return (uint16_t)((x + 0x7FFFu + ((x >> 16) & 1u)) >> 16);
}
__device__ __forceinline__ uint32_t pack2(float lo, float hi) {
    return (uint32_t)f2bf(lo) | ((uint32_t)f2bf(hi) << 16);
}
__device__ __forceinline__ void fmaC(const float4& cA, const float4& cB, float xs,
                                     float* __restrict__ acc) {
    acc[0] = fmaf(cA.x, xs, acc[0]); acc[1] = fmaf(cA.y, xs, acc[1]);
    acc[2] = fmaf(cA.z, xs, acc[2]); acc[3] = fmaf(cA.w, xs, acc[3]);
    acc[4] = fmaf(cB.x, xs, acc[4]); acc[5] = fmaf(cB.y, xs, acc[5]);
    acc[6] = fmaf(cB.z, xs, acc[6]); acc[7] = fmaf(cB.w, xs, acc[7]);
}

// ---------------------------------------------------------------------------
// cast: f32 feats -> bf16 x  (4 elems/thread)
// ---------------------------------------------------------------------------
__global__ void cast_kernel(const float* __restrict__ in, uint16_t* __restrict__ out, int n4) {
    const int stride = (int)(gridDim.x * blockDim.x);
    for (int idx = (int)(blockIdx.x * blockDim.x + threadIdx.x); idx < n4; idx += stride) {
        float4 v = reinterpret_cast<const float4*>(in)[idx];
        uint2 p;
        p.x = pack2(v.x, v.y);
        p.y = pack2(v.z, v.w);
        reinterpret_cast<uint2*>(out)[idx] = p;
    }
}

// ---------------------------------------------------------------------------
// CSR build, XCD-partitioned (round-16 measured form: scatter 78->58 us).
// rec[e] = { src | (etype<<20), norm }  (8 B)
// ---------------------------------------------------------------------------
__global__ void zero_kernel(int* __restrict__ p, int n) {
    for (int i = (int)(blockIdx.x * blockDim.x + threadIdx.x); i < n;
         i += (int)(gridDim.x * blockDim.x)) p[i] = 0;
}

__global__ void hist_kernel(const int* __restrict__ dst, int* __restrict__ cnt, int nE) {
    const int r     = (int)blockIdx.x & (NRANGE - 1);
    const int chunk = (int)blockIdx.x >> 3;
    const int nchk  = (int)gridDim.x >> 3;
    const int CH    = (nE + nchk - 1) / nchk;
    const int lo    = r * RANGE;
    const int hi    = (lo + RANGE < NNODES) ? lo + RANGE : NNODES;
    const int e1    = ((chunk + 1) * CH < nE) ? (chunk + 1) * CH : nE;
    for (int e = chunk * CH + (int)threadIdx.x; e < e1; e += 256) {
        const int d = dst[e];
        if (d >= lo && d < hi) atomicAdd(&cnt[d * CPAD], 1);
    }
}

#define SCAN_B 512
__launch_bounds__(SCAN_B)
__global__ void scan_partial_kernel(const int* __restrict__ cnt, int* __restrict__ bsum, int n) {
    __shared__ int sh[SCAN_B];
    int id = (int)(blockIdx.x * SCAN_B + threadIdx.x);
    sh[threadIdx.x] = (id < n) ? cnt[id * CPAD] : 0;
    __syncthreads();
    for (int off = SCAN_B / 2; off > 0; off >>= 1) {
        if ((int)threadIdx.x < off) sh[threadIdx.x] += sh[threadIdx.x + off];
        __syncthreads();
    }
    if (threadIdx.x == 0) bsum[blockIdx.x] = sh[0];
}

__launch_bounds__(256)
__global__ void scan_base_kernel(const int* __restrict__ bsum, int* __restrict__ bbase,
                                 int* __restrict__ offs, int nblk, int nNodes) {
    __shared__ int sh[256];
    const int t = (int)threadIdx.x;
    int v = (t < nblk) ? bsum[t] : 0;
    sh[t] = v;
    __syncthreads();
    for (int off = 1; off < 256; off <<= 1) {
        int tmp = (t >= off) ? sh[t - off] : 0;
        __syncthreads();
        sh[t] += tmp;
        __syncthreads();
    }
    if (t < nblk) bbase[t] = sh[t] - v;       // exclusive base per block
    if (t == 255) offs[nNodes] = sh[255];     // grand total
}

__launch_bounds__(SCAN_B)
__global__ void scan_final_kernel(int* __restrict__ cnt, const int* __restrict__ bbase,
                                  int* __restrict__ offs, int n) {
    __shared__ int sh[SCAN_B];
    int id = (int)(blockIdx.x * SCAN_B + threadIdx.x);
    int v = (id < n) ? cnt[id * CPAD] : 0;
    sh[threadIdx.x] = v;
    __syncthreads();
    for (int off = 1; off < SCAN_B; off <<= 1) {
        int tmp = ((int)threadIdx.x >= off) ? sh[threadIdx.x - off] : 0;
        __syncthreads();
        sh[threadIdx.x] += tmp;
        __syncthreads();
    }
    if (id < n) {
        int excl = sh[threadIdx.x] - v + bbase[blockIdx.x];
        offs[id] = excl;
        cnt[id * CPAD] = excl;   // becomes the scatter cursor
    }
}

__global__ void scatter_kernel(const int* __restrict__ src, const int* __restrict__ dst,
                               const int* __restrict__ et, const float* __restrict__ norm,
                               int* __restrict__ cursor, uint2* __restrict__ rec, int nE) {
    const int r     = (int)blockIdx.x & (NRANGE - 1);
    const int chunk = (int)blockIdx.x >> 3;
    const int nchk  = (int)gridDim.x >> 3;
    const int CH    = (nE + nchk - 1) / nchk;
    const int lo    = r * RANGE;
    const int hi    = (lo + RANGE < NNODES) ? lo + RANGE : NNODES;
    const int e1    = ((chunk + 1) * CH < nE) ? (chunk + 1) * CH : nE;
    for (int e = chunk * CH + (int)threadIdx.x; e < e1; e += 256) {
        const int d = dst[e];
        if (d >= lo && d < hi) {
            int p = atomicAdd(&cursor[d * CPAD], 1);
            rec[p] = make_uint2((uint32_t)src[e] | ((uint32_t)et[e] << 20), asu(norm[e]));
        }
    }
}

// ---------------------------------------------------------------------------
// Degree-sorted node permutation (perf-only; G output is per-node identical).
// Buckets DESCENDING by degree so paired half-waves get similar-degree nodes
// (kills the max(deg1,deg2) divergence ~25% issue waste) and big nodes
// schedule first (better tail).
// ---------------------------------------------------------------------------
__global__ void deg_zero_kernel(int* __restrict__ p) {
    if (threadIdx.x < 128) p[threadIdx.x] = 0;
}

__global__ void deg_hist_kernel(const int* __restrict__ offs, int* __restrict__ dcnt, int n) {
    for (int d = (int)(blockIdx.x * blockDim.x + threadIdx.x); d < n;
         d += (int)(gridDim.x * blockDim.x)) {
        int deg = offs[d + 1] - offs[d];
        int b = (deg > 63) ? 0 : (63 - deg);
        atomicAdd(&dcnt[b], 1);
    }
}

__launch_bounds__(64)
__global__ void deg_scan_kernel(const int* __restrict__ dcnt, int* __restrict__ dcur) {
    int t = (int)threadIdx.x;        // one wave, 64 lanes
    int v = dcnt[t];
    int s = v;
    for (int off = 1; off < 64; off <<= 1) {
        int u = __shfl_up(s, off);
        if (t >= off) s += u;
    }
    dcur[t] = s - v;                 // exclusive prefix
}

__global__ void deg_scatter_kernel(const int* __restrict__ offs, int* __restrict__ dcur,
                                   int* __restrict__ perm, int n) {
    for (int d = (int)(blockIdx.x * blockDim.x + threadIdx.x); d < n;
         d += (int)(gridDim.x * blockDim.x)) {
        int deg = offs[d + 1] - offs[d];
        int b = (deg > 63) ? 0 : (63 - deg);
        int p = atomicAdd(&dcur[b], 1);
        perm[p] = d;
    }
}

// ---------------------------------------------------------------------------
// Input-space aggregation (round-16 measured 53.9us form + perm indexing):
// HALF-WAVE per dst node; unroll-8 => 16 independent x-gathers per wave in
// flight. coeff staged in LDS. d = perm[i] (degree-sorted) -> paired
// half-waves have similar degree. Edge/FMA order per node identical ->
// bit-identical G.
// ---------------------------------------------------------------------------
__launch_bounds__(256)
__global__ void csr_agg_kernel(const uint16_t* __restrict__ x,
                               const float* __restrict__ coeff,
                               const int* __restrict__ offs,
                               const uint2* __restrict__ rec,
                               const int* __restrict__ perm,
                               uint16_t* __restrict__ G, int nNodes) {
    __shared__ __align__(16) float cS[NREL * NB];   // 2880 B
    for (int i = (int)threadIdx.x; i < NREL * NB; i += 256) cS[i] = coeff[i];
    __syncthreads();

    const int hl   = (int)threadIdx.x & 31;   // lane within half-wave
    const int hwid = (int)((blockIdx.x * blockDim.x + threadIdx.x) >> 5);
    const int nhw  = (int)((gridDim.x * blockDim.x) >> 5);

    for (int i = hwid; i < nNodes; i += nhw) {
        const int d = perm[i];
        const int j0 = offs[d], j1 = offs[d + 1];
        float accL[NB] = {0.f, 0.f, 0.f, 0.f, 0.f, 0.f, 0.f, 0.f};  // i = 2*hl
        float accH[NB] = {0.f, 0.f, 0.f, 0.f, 0.f, 0.f, 0.f, 0.f};  // i = 2*hl+1
        int j = j0;
        for (; j + 8 <= j1; j += 8) {
            uint2 r[8];
#pragma unroll
            for (int u = 0; u < 8; u++) r[u] = rec[j + u];
            uint32_t w[8];
#pragma unroll
            for (int u = 0; u < 8; u++)
                w[u] = *reinterpret_cast<const uint32_t*>(
                    x + (size_t)(r[u].x & 0xFFFFFu) * HDIM + 2 * hl);
#pragma unroll
            for (int u = 0; u < 8; u++) {
                const float4 cA = *reinterpret_cast<const float4*>(cS + (r[u].x >> 20) * NB);
                const float4 cB = *reinterpret_cast<const float4*>(cS + (r[u].x >> 20) * NB + 4);
                const float nm = asf(r[u].y);
                fmaC(cA, cB, asf(w[u] << 16) * nm, accL);
                fmaC(cA, cB, asf(w[u] & 0xFFFF0000u) * nm, accH);
            }
        }
        for (; j < j1; j++) {
            const uint2 r0 = rec[j];
            const uint32_t w0 = *reinterpret_cast<const uint32_t*>(
                x + (size_t)(r0.x & 0xFFFFFu) * HDIM + 2 * hl);
            const float4 cA = *reinterpret_cast<const float4*>(cS + (r0.x >> 20) * NB);
            const float4 cB = *reinterpret_cast<const float4*>(cS + (r0.x >> 20) * NB + 4);
            const float nm = asf(r0.y);
            fmaC(cA, cB, asf(w0 << 16) * nm, accL);
            fmaC(cA, cB, asf(w0 & 0xFFFF0000u) * nm, accH);
        }
        // lane hl owns k = 16*hl .. 16*hl+15 (i=2hl -> b0..7, i=2hl+1 -> b0..7)
        uint4 lo, hi;
        lo.x = pack2(accL[0], accL[1]); lo.y = pack2(accL[2], accL[3]);
        lo.z = pack2(accL[4], accL[5]); lo.w = pack2(accL[6], accL[7]);
        hi.x = pack2(accH[0], accH[1]); hi.y = pack2(accH[2], accH[3]);
        hi.z = pack2(accH[4], accH[5]); hi.w = pack2(accH[6], accH[7]);
        uint16_t* gp = G + (size_t)d * KDIM + hl * 16;
        *reinterpret_cast<uint4*>(gp)     = lo;
        *reinterpret_cast<uint4*>(gp + 8) = hi;
    }
}

// ---------------------------------------------------------------------------
// proj_hidden HYBRID (measured good round 15): 256-thread blocks, register
// B-panel per wave (wave = o-tile) + 64-row G tile staged once in XOR-
// swizzled LDS shared by all 4 waves -> G HBM-read 1x.
// ---------------------------------------------------------------------------
__launch_bounds__(256, 2)
__global__ void proj_hidden_kernel(const uint16_t* __restrict__ G,
                                   const float* __restrict__ bases,
                                   const float* __restrict__ bias,
                                   uint16_t* __restrict__ xout, int nNodes) {
    __shared__ __align__(16) uint4 Gs4[64 * 64];   // 64 rows x 64 granules = 64 KB

    const int t    = (int)threadIdx.x;
    const int lane = t & 63;
    const int ot   = t >> 6;            // wave = o-tile (0..3)
    const int q    = lane >> 4;
    const int c    = lane & 15;

    FragU bf[16];
#pragma unroll
    for (int kb = 0; kb < 16; kb++) {
#pragma unroll
        for (int j = 0; j < 8; j++) {
            const int k = kb * 32 + q * 8 + j;
            const int i = k >> 3, b = k & 7;
            bf[kb].s[j] = (short)f2bf(bases[(size_t)(b * HDIM + i) * HDIM + ot * 16 + c]);
        }
    }
    const float bv = bias[ot * 16 + c];

    const int nTiles = (nNodes + 63) / 64;
    for (int tile = (int)blockIdx.x; tile < nTiles; tile += (int)gridDim.x) {
        // ---- stage G tile (64 rows x 1024 B), swizzled granules
        for (int idx = t; idx < 64 * 64; idx += 256) {
            const int row = idx >> 6, g = idx & 63;
            int arow = tile * 64 + row;
            if (arow > nNodes - 1) arow = nNodes - 1;
            Gs4[(row << 6) | (g ^ (row & 7))] =
                *reinterpret_cast<const uint4*>(G + (size_t)arow * KDIM + g * 8);
        }
        __syncthreads();

        // ---- 4 row-groups per wave, A-frags from LDS
#pragma unroll
        for (int g = 0; g < 4; g++) {
            const int row = g * 16 + c;
            f32x4 acc = {0.f, 0.f, 0.f, 0.f};
#pragma unroll
            for (int kb = 0; kb < 16; kb++) {
                FragU a;
                a.u = Gs4[(row << 6) | ((kb * 4 + q) ^ (row & 7))];
                acc = __builtin_amdgcn_mfma_f32_16x16x32_bf16(a.s, bf[kb].s, acc, 0, 0, 0);
            }
            const int nbase = tile * 64 + g * 16 + q * 4;
#pragma unroll
            for (int r = 0; r < 4; r++) {
                const int node = nbase + r;
                if (node < nNodes) {
                    float v = fmaxf(acc[r] + bv, 0.f);
                    xout[(size_t)node * HDIM + ot * 16 + c] = f2bf(v);
                }
            }
        }
        __syncthreads();   // Gs4 reused next tile
    }
}

// ---------------------------------------------------------------------------
// proj_out: register-resident B-panel (measured good): each wave reads
// distinct rows -> G read once. Unchanged.
// ---------------------------------------------------------------------------
__launch_bounds__(256, 3)
__global__ void proj_out_kernel(const uint16_t* __restrict__ G,
                                const float* __restrict__ bases,
                                const float* __restrict__ bias,
                                float* __restrict__ out, int nNodes) {
    const int t    = (int)threadIdx.x;
    const int lane = t & 63;
    const int w    = t >> 6;            // wave = node-group (0..3), single o-tile
    const int q    = lane >> 4;
    const int c    = lane & 15;

    FragU bf[16];
#pragma unroll
    for (int kb = 0; kb < 16; kb++) {
#pragma unroll
        for (int j = 0; j < 8; j++) {
            const int k = kb * 32 + q * 8 + j;
            const int i = k >> 3, b = k & 7;
            bf[kb].s[j] = (short)f2bf(bases[(size_t)(b * HDIM + i) * ODIM + c]);
        }
    }
    const float bv = bias[c];

    const int nTiles = (nNodes + 63) / 64;
    for (int tile = (int)blockIdx.x; tile < nTiles; tile += (int)gridDim.x) {
        int arow = tile * 64 + w * 16 + c;
        if (arow > nNodes - 1) arow = nNodes - 1;
        const uint16_t* gp = G + (size_t)arow * KDIM + q * 8;

        f32x4 acc = {0.f, 0.f, 0.f, 0.f};
#pragma unroll
        for (int kb = 0; kb < 16; kb++) {
            FragU a;
            a.u = *reinterpret_cast<const uint4*>(gp + kb * 32);
            acc = __builtin_amdgcn_mfma_f32_16x16x32_bf16(a.s, bf[kb].s, acc, 0, 0, 0);
        }

        const int nbase = tile * 64 + w * 16 + q * 4;
#pragma unroll
        for (int r = 0; r < 4; r++) {
            const int node = nbase + r;
            if (node < nNodes) out[(size_t)node * ODIM + c] = acc[r] + bv;
        }
    }
}

extern "C" void kernel_launch(void* const* d_in, const int* in_sizes, int n_in,
                              void* d_out, int out_size, void* d_ws, size_t ws_size,
                              hipStream_t stream) {
    const float* feats  = (const float*)d_in[0];
    const float* coeff0 = (const float*)d_in[1];
    const float* bases0 = (const float*)d_in[2];
    const float* bias0  = (const float*)d_in[3];
    const float* coeff1 = (const float*)d_in[4];
    const float* bases1 = (const float*)d_in[5];
    const float* bias1  = (const float*)d_in[6];
    const float* coeff2 = (const float*)d_in[7];
    const float* bases2 = (const float*)d_in[8];
    const float* bias2  = (const float*)d_in[9];
    const int*   src    = (const int*)d_in[10];
    const int*   dst    = (const int*)d_in[11];
    const int*   etype  = (const int*)d_in[12];
    const float* norm   = (const float*)d_in[13];
    float* out = (float*)d_out;

    char* base = (char*)d_ws;
    // layout: G 102.4MB | x 12.8MB | offs+perm | bsum | bbase | rec 8MB
    // cursor (6.4MB) and deg counters (512B @ +8MB) alias the dead G region
    // (G is first written by csr_agg, stream-ordered after CSR build).
    // perm (400KB) lives in the spare half of the offs region (800032B
    // allocated, offs needs 400004B).
    uint16_t* G = (uint16_t*)base;
    int* curs   = (int*)base;                                          // aliased, 6.4MB
    int* dcnt   = (int*)(base + 8000000);                              // aliased, 256B
    int* dcur   = dcnt + 64;                                           // aliased, 256B
    uint16_t* x = (uint16_t*)(base + (size_t)NNODES * KDIM * 2);       // +102,400,000
    const size_t OFF_OFFS  = 115200000;
    const size_t OFF_PERM  = OFF_OFFS + 400016;
    const size_t OFF_BSUM  = OFF_OFFS + 800032;
    const size_t OFF_BBASE = OFF_BSUM + 1024;
    const size_t OFF_REC   = OFF_BBASE + 1024;                         // ~116 MB
    int*   offs  = (int*)(base + OFF_OFFS);
    int*   perm  = (int*)(base + OFF_PERM);
    int*   bsum  = (int*)(base + OFF_BSUM);
    int*   bbase = (int*)(base + OFF_BBASE);
    uint2* rec   = (uint2*)(base + OFF_REC);

    const int nblk = (NNODES + SCAN_B - 1) / SCAN_B;   // 196 <= 256

    // ---- CSR build (graph identical across layers; built once per call)
    hipLaunchKernelGGL(zero_kernel, dim3(2048), dim3(256), 0, stream, curs, NNODES * CPAD);
    hipLaunchKernelGGL(hist_kernel, dim3(2048), dim3(256), 0, stream, dst, curs, NEDGES);
    hipLaunchKernelGGL(scan_partial_kernel, dim3(nblk), dim3(SCAN_B), 0, stream, curs, bsum, NNODES);
    hipLaunchKernelGGL(scan_base_kernel, dim3(1), dim3(256), 0, stream, bsum, bbase, offs, nblk, NNODES);
    hipLaunchKernelGGL(scan_final_kernel, dim3(nblk), dim3(SCAN_B), 0, stream, curs, bbase, offs, NNODES);
    hipLaunchKernelGGL(scatter_kernel, dim3(2048), dim3(256), 0, stream,
                       src, dst, etype, norm, curs, rec, NEDGES);

    // ---- degree-sorted node permutation (uses offs; G still dead)
    hipLaunchKernelGGL(deg_zero_kernel, dim3(1), dim3(128), 0, stream, dcnt);
    hipLaunchKernelGGL(deg_hist_kernel, dim3(256), dim3(256), 0, stream, offs, dcnt, NNODES);
    hipLaunchKernelGGL(deg_scan_kernel, dim3(1), dim3(64), 0, stream, dcnt, dcur);
    hipLaunchKernelGGL(deg_scatter_kernel, dim3(256), dim3(256), 0, stream, offs, dcur, perm, NNODES);

    // ---- x0 = bf16(feats)
    hipLaunchKernelGGL(cast_kernel, dim3(2048), dim3(256), 0, stream,
                       feats, x, NNODES * HDIM / 4);

    // ---- Layer 0
    hipLaunchKernelGGL(csr_agg_kernel, dim3(2048), dim3(256), 0, stream,
                       x, coeff0, offs, rec, perm, G, NNODES);
    hipLaunchKernelGGL(proj_hidden_kernel, dim3(1024), dim3(256), 0, stream,
                       G, bases0, bias0, x, NNODES);
    // ---- Layer 1
    hipLaunchKernelGGL(csr_agg_kernel, dim3(2048), dim3(256), 0, stream,
                       x, coeff1, offs, rec, perm, G, NNODES);
    hipLaunchKernelGGL(proj_hidden_kernel, dim3(1024), dim3(256), 0, stream,
                       G, bases1, bias1, x, NNODES);
    // ---- Layer 2
    hipLaunchKernelGGL(csr_agg_kernel, dim3(2048), dim3(256), 0, stream,
                       x, coeff2, offs, rec, perm, G, NNODES);
    hipLaunchKernelGGL(proj_out_kernel, dim3(1024), dim3(256), 0, stream,
                       G, bases2, bias2, out, NNODES);
}

// Round 23
// 448.656 us; speedup vs baseline: 2.4362x; 2.4362x over previous
//
#include <hip/hip_runtime.h>
#include <hip/hip_bf16.h>
#include <cstdint>

#define NNODES 100000
#define NEDGES 1000000
#define HDIM 64
#define ODIM 16
#define NB 8
#define NREL 90
#define KDIM (HDIM * NB)   // 512 = GEMM inner dim, k = i*8 + b
#define CPAD 16            // cursor padding: one counter per 64B line
#define NRANGE 8           // dst ranges (== XCD count heuristic)
#define RANGE ((NNODES + NRANGE - 1) / NRANGE)   // 12500 nodes/range

typedef short short8 __attribute__((ext_vector_type(8)));
typedef float f32x4  __attribute__((ext_vector_type(4)));
union FragU { uint4 u; short8 s; };

__device__ __forceinline__ float asf(uint32_t u) { float f; __builtin_memcpy(&f, &u, 4); return f; }
__device__ __forceinline__ uint32_t asu(float f) { uint32_t u; __builtin_memcpy(&u, &f, 4); return u; }
__device__ __forceinline__ uint16_t f2bf(float f) {
    uint32_t x = asu(f);
    return (uint16_t)((x + 0x7FFFu + ((x >> 16) & 1u)) >> 16);
}
__device__ __forceinline__ uint32_t pack2(float lo, float hi) {
    return (uint32_t)f2bf(lo) | ((uint32_t)f2bf(hi) << 16);
}
__device__ __forceinline__ void fmaC(const float4& cA, const float4& cB, float xs,
                                     float* __restrict__ acc) {
    acc[0] = fmaf(cA.x, xs, acc[0]); acc[1] = fmaf(cA.y, xs, acc[1]);
    acc[2] = fmaf(cA.z, xs, acc[2]); acc[3] = fmaf(cA.w, xs, acc[3]);
    acc[4] = fmaf(cB.x, xs, acc[4]); acc[5] = fmaf(cB.y, xs, acc[5]);
    acc[6] = fmaf(cB.z, xs, acc[6]); acc[7] = fmaf(cB.w, xs, acc[7]);
}

// ---------------------------------------------------------------------------
// cast: f32 feats -> bf16 x  (4 elems/thread)
// ---------------------------------------------------------------------------
__global__ void cast_kernel(const float* __restrict__ in, uint16_t* __restrict__ out, int n4) {
    const int stride = (int)(gridDim.x * blockDim.x);
    for (int idx = (int)(blockIdx.x * blockDim.x + threadIdx.x); idx < n4; idx += stride) {
        float4 v = reinterpret_cast<const float4*>(in)[idx];
        uint2 p;
        p.x = pack2(v.x, v.y);
        p.y = pack2(v.z, v.w);
        reinterpret_cast<uint2*>(out)[idx] = p;
    }
}

// ---------------------------------------------------------------------------
// CSR build, XCD-partitioned (round-16 measured form: scatter 78->58 us).
// rec[e] = { src | (etype<<20), norm }  (8 B)
// ---------------------------------------------------------------------------
__global__ void zero_kernel(int* __restrict__ p, int n) {
    for (int i = (int)(blockIdx.x * blockDim.x + threadIdx.x); i < n;
         i += (int)(gridDim.x * blockDim.x)) p[i] = 0;
}

__global__ void hist_kernel(const int* __restrict__ dst, int* __restrict__ cnt, int nE) {
    const int r     = (int)blockIdx.x & (NRANGE - 1);
    const int chunk = (int)blockIdx.x >> 3;
    const int nchk  = (int)gridDim.x >> 3;
    const int CH    = (nE + nchk - 1) / nchk;
    const int lo    = r * RANGE;
    const int hi    = (lo + RANGE < NNODES) ? lo + RANGE : NNODES;
    const int e1    = ((chunk + 1) * CH < nE) ? (chunk + 1) * CH : nE;
    for (int e = chunk * CH + (int)threadIdx.x; e < e1; e += 256) {
        const int d = dst[e];
        if (d >= lo && d < hi) atomicAdd(&cnt[d * CPAD], 1);
    }
}

#define SCAN_B 512
__launch_bounds__(SCAN_B)
__global__ void scan_partial_kernel(const int* __restrict__ cnt, int* __restrict__ bsum, int n) {
    __shared__ int sh[SCAN_B];
    int id = (int)(blockIdx.x * SCAN_B + threadIdx.x);
    sh[threadIdx.x] = (id < n) ? cnt[id * CPAD] : 0;
    __syncthreads();
    for (int off = SCAN_B / 2; off > 0; off >>= 1) {
        if ((int)threadIdx.x < off) sh[threadIdx.x] += sh[threadIdx.x + off];
        __syncthreads();
    }
    if (threadIdx.x == 0) bsum[blockIdx.x] = sh[0];
}

__launch_bounds__(256)
__global__ void scan_base_kernel(const int* __restrict__ bsum, int* __restrict__ bbase,
                                 int* __restrict__ offs, int nblk, int nNodes) {
    __shared__ int sh[256];
    const int t = (int)threadIdx.x;
    int v = (t < nblk) ? bsum[t] : 0;
    sh[t] = v;
    __syncthreads();
    for (int off = 1; off < 256; off <<= 1) {
        int tmp = (t >= off) ? sh[t - off] : 0;
        __syncthreads();
        sh[t] += tmp;
        __syncthreads();
    }
    if (t < nblk) bbase[t] = sh[t] - v;       // exclusive base per block
    if (t == 255) offs[nNodes] = sh[255];     // grand total
}

__launch_bounds__(SCAN_B)
__global__ void scan_final_kernel(int* __restrict__ cnt, const int* __restrict__ bbase,
                                  int* __restrict__ offs, int n) {
    __shared__ int sh[SCAN_B];
    int id = (int)(blockIdx.x * SCAN_B + threadIdx.x);
    int v = (id < n) ? cnt[id * CPAD] : 0;
    sh[threadIdx.x] = v;
    __syncthreads();
    for (int off = 1; off < SCAN_B; off <<= 1) {
        int tmp = ((int)threadIdx.x >= off) ? sh[threadIdx.x - off] : 0;
        __syncthreads();
        sh[threadIdx.x] += tmp;
        __syncthreads();
    }
    if (id < n) {
        int excl = sh[threadIdx.x] - v + bbase[blockIdx.x];
        offs[id] = excl;
        cnt[id * CPAD] = excl;   // becomes the scatter cursor
    }
}

__global__ void scatter_kernel(const int* __restrict__ src, const int* __restrict__ dst,
                               const int* __restrict__ et, const float* __restrict__ norm,
                               int* __restrict__ cursor, uint2* __restrict__ rec, int nE) {
    const int r     = (int)blockIdx.x & (NRANGE - 1);
    const int chunk = (int)blockIdx.x >> 3;
    const int nchk  = (int)gridDim.x >> 3;
    const int CH    = (nE + nchk - 1) / nchk;
    const int lo    = r * RANGE;
    const int hi    = (lo + RANGE < NNODES) ? lo + RANGE : NNODES;
    const int e1    = ((chunk + 1) * CH < nE) ? (chunk + 1) * CH : nE;
    for (int e = chunk * CH + (int)threadIdx.x; e < e1; e += 256) {
        const int d = dst[e];
        if (d >= lo && d < hi) {
            int p = atomicAdd(&cursor[d * CPAD], 1);
            rec[p] = make_uint2((uint32_t)src[e] | ((uint32_t)et[e] << 20), asu(norm[e]));
        }
    }
}

// ---------------------------------------------------------------------------
// Degree-sorted node permutation, TWO-LEVEL (round-22's flat version spent
// 330us/call on 100K atomics to 64 unpadded counters — same-address atomic
// serialization, the round-10 pathology reborn). Now: per-block LDS histogram
// -> 64 global atomics/block onto LINE-PADDED counters (256/counter, ~2us)
// -> local LDS-cursor scatter. perm is still a permutation -> bit-identical G
// (per-node work is order-independent).
// Bucket b = 63 - min(deg,63): DESCENDING degree.
// ---------------------------------------------------------------------------
__global__ void deg_zero_kernel(int* __restrict__ p, int n) {
    for (int i = (int)(blockIdx.x * blockDim.x + threadIdx.x); i < n;
         i += (int)(gridDim.x * blockDim.x)) p[i] = 0;
}

__launch_bounds__(256)
__global__ void deg_hist_kernel(const int* __restrict__ offs, int* __restrict__ dcnt, int n) {
    __shared__ int lc[64];
    const int t = (int)threadIdx.x;
    if (t < 64) lc[t] = 0;
    __syncthreads();
    const int CH = (n + (int)gridDim.x - 1) / (int)gridDim.x;
    const int d0 = (int)blockIdx.x * CH;
    const int d1 = (d0 + CH < n) ? d0 + CH : n;
    for (int d = d0 + t; d < d1; d += 256) {
        int deg = offs[d + 1] - offs[d];
        int b = (deg > 63) ? 0 : (63 - deg);
        atomicAdd(&lc[b], 1);
    }
    __syncthreads();
    if (t < 64 && lc[t] > 0) atomicAdd(&dcnt[t * CPAD], lc[t]);
}

__launch_bounds__(64)
__global__ void deg_scan_kernel(const int* __restrict__ dcnt, int* __restrict__ dcur) {
    int t = (int)threadIdx.x;        // one wave, 64 lanes
    int v = dcnt[t * CPAD];
    int s = v;
    for (int off = 1; off < 64; off <<= 1) {
        int u = __shfl_up(s, off);
        if (t >= off) s += u;
    }
    dcur[t * CPAD] = s - v;          // exclusive prefix
}

__launch_bounds__(256)
__global__ void deg_scatter_kernel(const int* __restrict__ offs, int* __restrict__ dcur,
                                   int* __restrict__ perm, int n) {
    __shared__ int lc[64];     // local counts, then local cursors
    __shared__ int lb[64];     // global base per bucket for this block
    const int t = (int)threadIdx.x;
    if (t < 64) lc[t] = 0;
    __syncthreads();
    const int CH = (n + (int)gridDim.x - 1) / (int)gridDim.x;
    const int d0 = (int)blockIdx.x * CH;
    const int d1 = (d0 + CH < n) ? d0 + CH : n;
    for (int d = d0 + t; d < d1; d += 256) {
        int deg = offs[d + 1] - offs[d];
        int b = (deg > 63) ? 0 : (63 - deg);
        atomicAdd(&lc[b], 1);
    }
    __syncthreads();
    if (t < 64) {
        lb[t] = (lc[t] > 0) ? atomicAdd(&dcur[t * CPAD], lc[t]) : 0;
        lc[t] = 0;             // becomes local cursor
    }
    __syncthreads();
    for (int d = d0 + t; d < d1; d += 256) {
        int deg = offs[d + 1] - offs[d];
        int b = (deg > 63) ? 0 : (63 - deg);
        int p = lb[b] + atomicAdd(&lc[b], 1);
        perm[p] = d;
    }
}

// ---------------------------------------------------------------------------
// Input-space aggregation (round-16 measured 53.9us form + perm indexing):
// HALF-WAVE per dst node; unroll-8 => 16 independent x-gathers per wave in
// flight. coeff staged in LDS. d = perm[i] (degree-sorted) -> paired
// half-waves have similar degree. Edge/FMA order per node identical ->
// bit-identical G.
// ---------------------------------------------------------------------------
__launch_bounds__(256)
__global__ void csr_agg_kernel(const uint16_t* __restrict__ x,
                               const float* __restrict__ coeff,
                               const int* __restrict__ offs,
                               const uint2* __restrict__ rec,
                               const int* __restrict__ perm,
                               uint16_t* __restrict__ G, int nNodes) {
    __shared__ __align__(16) float cS[NREL * NB];   // 2880 B
    for (int i = (int)threadIdx.x; i < NREL * NB; i += 256) cS[i] = coeff[i];
    __syncthreads();

    const int hl   = (int)threadIdx.x & 31;   // lane within half-wave
    const int hwid = (int)((blockIdx.x * blockDim.x + threadIdx.x) >> 5);
    const int nhw  = (int)((gridDim.x * blockDim.x) >> 5);

    for (int i = hwid; i < nNodes; i += nhw) {
        const int d = perm[i];
        const int j0 = offs[d], j1 = offs[d + 1];
        float accL[NB] = {0.f, 0.f, 0.f, 0.f, 0.f, 0.f, 0.f, 0.f};  // i = 2*hl
        float accH[NB] = {0.f, 0.f, 0.f, 0.f, 0.f, 0.f, 0.f, 0.f};  // i = 2*hl+1
        int j = j0;
        for (; j + 8 <= j1; j += 8) {
            uint2 r[8];
#pragma unroll
            for (int u = 0; u < 8; u++) r[u] = rec[j + u];
            uint32_t w[8];
#pragma unroll
            for (int u = 0; u < 8; u++)
                w[u] = *reinterpret_cast<const uint32_t*>(
                    x + (size_t)(r[u].x & 0xFFFFFu) * HDIM + 2 * hl);
#pragma unroll
            for (int u = 0; u < 8; u++) {
                const float4 cA = *reinterpret_cast<const float4*>(cS + (r[u].x >> 20) * NB);
                const float4 cB = *reinterpret_cast<const float4*>(cS + (r[u].x >> 20) * NB + 4);
                const float nm = asf(r[u].y);
                fmaC(cA, cB, asf(w[u] << 16) * nm, accL);
                fmaC(cA, cB, asf(w[u] & 0xFFFF0000u) * nm, accH);
            }
        }
        for (; j < j1; j++) {
            const uint2 r0 = rec[j];
            const uint32_t w0 = *reinterpret_cast<const uint32_t*>(
                x + (size_t)(r0.x & 0xFFFFFu) * HDIM + 2 * hl);
            const float4 cA = *reinterpret_cast<const float4*>(cS + (r0.x >> 20) * NB);
            const float4 cB = *reinterpret_cast<const float4*>(cS + (r0.x >> 20) * NB + 4);
            const float nm = asf(r0.y);
            fmaC(cA, cB, asf(w0 << 16) * nm, accL);
            fmaC(cA, cB, asf(w0 & 0xFFFF0000u) * nm, accH);
        }
        // lane hl owns k = 16*hl .. 16*hl+15 (i=2hl -> b0..7, i=2hl+1 -> b0..7)
        uint4 lo, hi;
        lo.x = pack2(accL[0], accL[1]); lo.y = pack2(accL[2], accL[3]);
        lo.z = pack2(accL[4], accL[5]); lo.w = pack2(accL[6], accL[7]);
        hi.x = pack2(accH[0], accH[1]); hi.y = pack2(accH[2], accH[3]);
        hi.z = pack2(accH[4], accH[5]); hi.w = pack2(accH[6], accH[7]);
        uint16_t* gp = G + (size_t)d * KDIM + hl * 16;
        *reinterpret_cast<uint4*>(gp)     = lo;
        *reinterpret_cast<uint4*>(gp + 8) = hi;
    }
}

// ---------------------------------------------------------------------------
// proj_hidden HYBRID (measured good round 15): 256-thread blocks, register
// B-panel per wave (wave = o-tile) + 64-row G tile staged once in XOR-
// swizzled LDS shared by all 4 waves -> G HBM-read 1x.
// ---------------------------------------------------------------------------
__launch_bounds__(256, 2)
__global__ void proj_hidden_kernel(const uint16_t* __restrict__ G,
                                   const float* __restrict__ bases,
                                   const float* __restrict__ bias,
                                   uint16_t* __restrict__ xout, int nNodes) {
    __shared__ __align__(16) uint4 Gs4[64 * 64];   // 64 rows x 64 granules = 64 KB

    const int t    = (int)threadIdx.x;
    const int lane = t & 63;
    const int ot   = t >> 6;            // wave = o-tile (0..3)
    const int q    = lane >> 4;
    const int c    = lane & 15;

    FragU bf[16];
#pragma unroll
    for (int kb = 0; kb < 16; kb++) {
#pragma unroll
        for (int j = 0; j < 8; j++) {
            const int k = kb * 32 + q * 8 + j;
            const int i = k >> 3, b = k & 7;
            bf[kb].s[j] = (short)f2bf(bases[(size_t)(b * HDIM + i) * HDIM + ot * 16 + c]);
        }
    }
    const float bv = bias[ot * 16 + c];

    const int nTiles = (nNodes + 63) / 64;
    for (int tile = (int)blockIdx.x; tile < nTiles; tile += (int)gridDim.x) {
        // ---- stage G tile (64 rows x 1024 B), swizzled granules
        for (int idx = t; idx < 64 * 64; idx += 256) {
            const int row = idx >> 6, g = idx & 63;
            int arow = tile * 64 + row;
            if (arow > nNodes - 1) arow = nNodes - 1;
            Gs4[(row << 6) | (g ^ (row & 7))] =
                *reinterpret_cast<const uint4*>(G + (size_t)arow * KDIM + g * 8);
        }
        __syncthreads();

        // ---- 4 row-groups per wave, A-frags from LDS
#pragma unroll
        for (int g = 0; g < 4; g++) {
            const int row = g * 16 + c;
            f32x4 acc = {0.f, 0.f, 0.f, 0.f};
#pragma unroll
            for (int kb = 0; kb < 16; kb++) {
                FragU a;
                a.u = Gs4[(row << 6) | ((kb * 4 + q) ^ (row & 7))];
                acc = __builtin_amdgcn_mfma_f32_16x16x32_bf16(a.s, bf[kb].s, acc, 0, 0, 0);
            }
            const int nbase = tile * 64 + g * 16 + q * 4;
#pragma unroll
            for (int r = 0; r < 4; r++) {
                const int node = nbase + r;
                if (node < nNodes) {
                    float v = fmaxf(acc[r] + bv, 0.f);
                    xout[(size_t)node * HDIM + ot * 16 + c] = f2bf(v);
                }
            }
        }
        __syncthreads();   // Gs4 reused next tile
    }
}

// ---------------------------------------------------------------------------
// proj_out: register-resident B-panel (measured good): each wave reads
// distinct rows -> G read once. Unchanged.
// ---------------------------------------------------------------------------
__launch_bounds__(256, 3)
__global__ void proj_out_kernel(const uint16_t* __restrict__ G,
                                const float* __restrict__ bases,
                                const float* __restrict__ bias,
                                float* __restrict__ out, int nNodes) {
    const int t    = (int)threadIdx.x;
    const int lane = t & 63;
    const int w    = t >> 6;            // wave = node-group (0..3), single o-tile
    const int q    = lane >> 4;
    const int c    = lane & 15;

    FragU bf[16];
#pragma unroll
    for (int kb = 0; kb < 16; kb++) {
#pragma unroll
        for (int j = 0; j < 8; j++) {
            const int k = kb * 32 + q * 8 + j;
            const int i = k >> 3, b = k & 7;
            bf[kb].s[j] = (short)f2bf(bases[(size_t)(b * HDIM + i) * ODIM + c]);
        }
    }
    const float bv = bias[c];

    const int nTiles = (nNodes + 63) / 64;
    for (int tile = (int)blockIdx.x; tile < nTiles; tile += (int)gridDim.x) {
        int arow = tile * 64 + w * 16 + c;
        if (arow > nNodes - 1) arow = nNodes - 1;
        const uint16_t* gp = G + (size_t)arow * KDIM + q * 8;

        f32x4 acc = {0.f, 0.f, 0.f, 0.f};
#pragma unroll
        for (int kb = 0; kb < 16; kb++) {
            FragU a;
            a.u = *reinterpret_cast<const uint4*>(gp + kb * 32);
            acc = __builtin_amdgcn_mfma_f32_16x16x32_bf16(a.s, bf[kb].s, acc, 0, 0, 0);
        }

        const int nbase = tile * 64 + w * 16 + q * 4;
#pragma unroll
        for (int r = 0; r < 4; r++) {
            const int node = nbase + r;
            if (node < nNodes) out[(size_t)node * ODIM + c] = acc[r] + bv;
        }
    }
}

extern "C" void kernel_launch(void* const* d_in, const int* in_sizes, int n_in,
                              void* d_out, int out_size, void* d_ws, size_t ws_size,
                              hipStream_t stream) {
    const float* feats  = (const float*)d_in[0];
    const float* coeff0 = (const float*)d_in[1];
    const float* bases0 = (const float*)d_in[2];
    const float* bias0  = (const float*)d_in[3];
    const float* coeff1 = (const float*)d_in[4];
    const float* bases1 = (const float*)d_in[5];
    const float* bias1  = (const float*)d_in[6];
    const float* coeff2 = (const float*)d_in[7];
    const float* bases2 = (const float*)d_in[8];
    const float* bias2  = (const float*)d_in[9];
    const int*   src    = (const int*)d_in[10];
    const int*   dst    = (const int*)d_in[11];
    const int*   etype  = (const int*)d_in[12];
    const float* norm   = (const float*)d_in[13];
    float* out = (float*)d_out;

    char* base = (char*)d_ws;
    // layout: G 102.4MB | x 12.8MB | offs+perm | bsum | bbase | rec 8MB
    // cursor (6.4MB) and deg counters (8KB padded @ +8MB) alias the dead G
    // region (G first written by csr_agg, stream-ordered after CSR build).
    // perm (400KB) lives in the spare half of the offs region.
    uint16_t* G = (uint16_t*)base;
    int* curs   = (int*)base;                                          // aliased, 6.4MB
    int* dcnt   = (int*)(base + 8000000);                              // aliased, 4KB padded
    int* dcur   = dcnt + 64 * CPAD;                                    // aliased, 4KB padded
    uint16_t* x = (uint16_t*)(base + (size_t)NNODES * KDIM * 2);       // +102,400,000
    const size_t OFF_OFFS  = 115200000;
    const size_t OFF_PERM  = OFF_OFFS + 400016;
    const size_t OFF_BSUM  = OFF_OFFS + 800032;
    const size_t OFF_BBASE = OFF_BSUM + 1024;
    const size_t OFF_REC   = OFF_BBASE + 1024;                         // ~116 MB
    int*   offs  = (int*)(base + OFF_OFFS);
    int*   perm  = (int*)(base + OFF_PERM);
    int*   bsum  = (int*)(base + OFF_BSUM);
    int*   bbase = (int*)(base + OFF_BBASE);
    uint2* rec   = (uint2*)(base + OFF_REC);

    const int nblk = (NNODES + SCAN_B - 1) / SCAN_B;   // 196 <= 256

    // ---- CSR build (graph identical across layers; built once per call)
    hipLaunchKernelGGL(zero_kernel, dim3(2048), dim3(256), 0, stream, curs, NNODES * CPAD);
    hipLaunchKernelGGL(hist_kernel, dim3(2048), dim3(256), 0, stream, dst, curs, NEDGES);
    hipLaunchKernelGGL(scan_partial_kernel, dim3(nblk), dim3(SCAN_B), 0, stream, curs, bsum, NNODES);
    hipLaunchKernelGGL(scan_base_kernel, dim3(1), dim3(256), 0, stream, bsum, bbase, offs, nblk, NNODES);
    hipLaunchKernelGGL(scan_final_kernel, dim3(nblk), dim3(SCAN_B), 0, stream, curs, bbase, offs, NNODES);
    hipLaunchKernelGGL(scatter_kernel, dim3(2048), dim3(256), 0, stream,
                       src, dst, etype, norm, curs, rec, NEDGES);

    // ---- degree-sorted node permutation (two-level; uses offs; G still dead)
    hipLaunchKernelGGL(deg_zero_kernel, dim3(8), dim3(256), 0, stream, dcnt, 2 * 64 * CPAD);
    hipLaunchKernelGGL(deg_hist_kernel, dim3(256), dim3(256), 0, stream, offs, dcnt, NNODES);
    hipLaunchKernelGGL(deg_scan_kernel, dim3(1), dim3(64), 0, stream, dcnt, dcur);
    hipLaunchKernelGGL(deg_scatter_kernel, dim3(256), dim3(256), 0, stream, offs, dcur, perm, NNODES);

    // ---- x0 = bf16(feats)
    hipLaunchKernelGGL(cast_kernel, dim3(2048), dim3(256), 0, stream,
                       feats, x, NNODES * HDIM / 4);

    // ---- Layer 0
    hipLaunchKernelGGL(csr_agg_kernel, dim3(2048), dim3(256), 0, stream,
                       x, coeff0, offs, rec, perm, G, NNODES);
    hipLaunchKernelGGL(proj_hidden_kernel, dim3(1024), dim3(256), 0, stream,
                       G, bases0, bias0, x, NNODES);
    // ---- Layer 1
    hipLaunchKernelGGL(csr_agg_kernel, dim3(2048), dim3(256), 0, stream,
                       x, coeff1, offs, rec, perm, G, NNODES);
    hipLaunchKernelGGL(proj_hidden_kernel, dim3(1024), dim3(256), 0, stream,
                       G, bases1, bias1, x, NNODES);
    // ---- Layer 2
    hipLaunchKernelGGL(csr_agg_kernel, dim3(2048), dim3(256), 0, stream,
                       x, coeff2, offs, rec, perm, G, NNODES);
    hipLaunchKernelGGL(proj_out_kernel, dim3(1024), dim3(256), 0, stream,
                       G, bases2, bias2, out, NNODES);
}